// Round 3
// baseline (1213.204 us; speedup 1.0000x reference)
//
#include <hip/hip_runtime.h>
#include <hip/hip_bf16.h>
#include <hip/hip_cooperative_groups.h>
#include <math.h>
#include <stdint.h>

namespace cg = cooperative_groups;

// TreeLSTM on MFMA: L=16384, D=256, 5 gates, 15 levels, proj to 5.
// Split-precision bf16 (hi+lo) GEMMs: A*B ~= Ahi*Bhi + Alo*Bhi + Ahi*Blo.
// R2: A wave-private -> global->VGPR dbuf; LDS holds only B (40KB).
// R3: levels 3..14 fused into ONE cooperative persistent kernel (no LDS,
//     no __syncthreads; grid.sync between levels; B/A direct from L2).

typedef __attribute__((ext_vector_type(8))) short     bf16x8;
typedef __attribute__((ext_vector_type(4))) float     f32x4;
typedef __attribute__((ext_vector_type(8))) unsigned short u16x8;

#define NGATE 5
#define TAIL_T0 3

__device__ __forceinline__ uint16_t f2bf(float f) {
    uint32_t u = __builtin_bit_cast(uint32_t, f);
    u = (u + 0x7fffu + ((u >> 16) & 1u)) >> 16;
    return (uint16_t)u;
}
__device__ __forceinline__ float bf2f(uint16_t h) {
    uint32_t u = ((uint32_t)h) << 16;
    return __builtin_bit_cast(float, u);
}
__device__ __forceinline__ float sigf(float x) { return 1.0f / (1.0f + __expf(-x)); }
__device__ __forceinline__ float tanhfast(float x) {
    float e = __expf(2.0f * x);          // bounded inputs (|x| < ~20) -> no inf
    return (e - 1.0f) / (e + 1.0f);
}

__device__ __forceinline__ void gld_lds16(const void* g, void* l) {
    __builtin_amdgcn_global_load_lds(
        (const __attribute__((address_space(1))) void*)g,
        (__attribute__((address_space(3))) void*)l,
        16, 0, 0);
}

// ---- pack weights into MFMA B-frag order, split hi/lo ----------------------
// dst[( nt*KT + kt )*64 + lane][j]  =  W[kt*32 + (lane>>4)*8 + j][nt*16 + (lane&15)]
// W rows: k<256 from W0, k>=256 from W1 (both row-major K x 1280).
__global__ __launch_bounds__(256) void pack_w_kernel(
    const float* __restrict__ W0, const float* __restrict__ W1, int KT,
    uint16_t* __restrict__ dhi, uint16_t* __restrict__ dlo)
{
    int gid = blockIdx.x * 256 + threadIdx.x;
    int total = 80 * KT * 64;
    if (gid >= total) return;
    int lane = gid & 63;
    int n  = ((gid >> 6) / KT) * 16 + (lane & 15);
    int kt = (gid >> 6) % KT;
    int k0 = kt * 32 + (lane >> 4) * 8;
    u16x8 vh, vl;
    #pragma unroll
    for (int j = 0; j < 8; ++j) {
        int k = k0 + j;
        const float* src = (k < 256) ? (W0 + (size_t)k * 1280)
                                     : (W1 + (size_t)(k - 256) * 1280);
        float v = src[n];
        uint16_t h = f2bf(v);
        vh[j] = h;
        vl[j] = f2bf(v - bf2f(h));
    }
    *(u16x8*)(dhi + (size_t)gid * 8) = vh;
    *(u16x8*)(dlo + (size_t)gid * 8) = vl;
}

// ---- fused level GEMM + LSTM cell (big levels: 0..TAIL_T0-1) ---------------
// Block: 256 thr = 4 waves. Tile: BM rows x (NGATE * JT * 16) cols.
// A fragments wave-private: global->VGPR double-buffered. B via LDS (dbuf).
template<int BM, int KT, int JT, bool LVL0>
__global__ __launch_bounds__(256) void lvl_gemm(
    const uint16_t* __restrict__ Ahi, const uint16_t* __restrict__ Alo, // row-major, stride K
    const int* __restrict__ tokens, const float* __restrict__ emb,      // LVL0 only
    const uint16_t* __restrict__ Bhi, const uint16_t* __restrict__ Blo, // packed frag order
    const float* __restrict__ b,
    const float* __restrict__ c_prev,                                    // null for LVL0
    uint16_t* __restrict__ h_hi_out, uint16_t* __restrict__ h_lo_out,
    float* __restrict__ c_out, int n)
{
    constexpr int K   = KT * 32;
    constexpr int MT  = BM / 64;          // m-tiles per wave
    constexpr int NC  = NGATE * JT * 2;   // B chunks per k-step (g x js x hi/lo)

    __shared__ __align__(16) uint16_t sB0[NC * 512];
    __shared__ __align__(16) uint16_t sB1[NC * 512];

    const int tid  = threadIdx.x;
    const int wave = tid >> 6;
    const int lane = tid & 63;
    const int quad = lane >> 4;
    const int l15  = lane & 15;
    const int r0   = blockIdx.x * BM;
    const int jn   = blockIdx.y;

    f32x4 acc[MT][JT][NGATE] = {};

    // per-lane A source pointers (fixed row, k advances by kt*32)
    const uint16_t* aph[MT];
    const uint16_t* apl[MT];
    const float*    ebase[MT];
    #pragma unroll
    for (int mt = 0; mt < MT; ++mt) {
        int row = r0 + (wave * MT + mt) * 16 + l15;
        row = min(row, n - 1);
        if constexpr (LVL0) {
            int tok = tokens[row];
            ebase[mt] = emb + (size_t)tok * 256 + quad * 8;
        } else {
            aph[mt] = Ahi + (size_t)row * K + quad * 8;
            apl[mt] = Alo + (size_t)row * K + quad * 8;
        }
    }

    auto stageB = [&](uint16_t* dB, int kt) {
        for (int c = wave; c < NC; c += 4) {
            int hl = c & 1, gj = c >> 1;                 // gj = g*JT + js
            const uint16_t* src = hl ? Blo : Bhi;
            int nt = (gj / JT) * 16 + jn * JT + (gj % JT);
            gld_lds16(src + ((size_t)(nt * KT + kt) * 64 + lane) * 8,
                      dB + c * 512);
        }
    };
    // level>=1: raw bf16x8 A loads
    auto loadAn = [&](bf16x8 (&ah)[MT], bf16x8 (&al)[MT], int kt) {
        #pragma unroll
        for (int mt = 0; mt < MT; ++mt) {
            ah[mt] = *(const bf16x8*)(aph[mt] + kt * 32);
            al[mt] = *(const bf16x8*)(apl[mt] + kt * 32);
        }
    };
    // level0: raw emb float loads (convert at consume time)
    auto loadA0 = [&](float4 (&e)[MT][2], int kt) {
        #pragma unroll
        for (int mt = 0; mt < MT; ++mt) {
            const float4* p = (const float4*)(ebase[mt] + kt * 32);
            e[mt][0] = p[0];
            e[mt][1] = p[1];
        }
    };
    auto cvtA0 = [&](const float4 (&e)[MT][2], bf16x8 (&ah)[MT], bf16x8 (&al)[MT]) {
        #pragma unroll
        for (int mt = 0; mt < MT; ++mt) {
            float fv[8];
            fv[0] = e[mt][0].x; fv[1] = e[mt][0].y; fv[2] = e[mt][0].z; fv[3] = e[mt][0].w;
            fv[4] = e[mt][1].x; fv[5] = e[mt][1].y; fv[6] = e[mt][1].z; fv[7] = e[mt][1].w;
            #pragma unroll
            for (int j = 0; j < 8; ++j) {
                uint16_t h = f2bf(fv[j]);
                ah[mt][j] = (short)h;
                al[mt][j] = (short)f2bf(fv[j] - bf2f(h));
            }
        }
    };
    auto mfma_all = [&](const bf16x8 (&ah)[MT], const bf16x8 (&al)[MT],
                        const uint16_t* Bx) {
        #pragma unroll
        for (int g = 0; g < NGATE; ++g) {
            #pragma unroll
            for (int js = 0; js < JT; ++js) {
                const uint16_t* bp = Bx + (g * JT + js) * 1024;
                bf16x8 bh = *(const bf16x8*)(bp + lane * 8);
                bf16x8 bl = *(const bf16x8*)(bp + 512 + lane * 8);
                #pragma unroll
                for (int mt = 0; mt < MT; ++mt) {
                    acc[mt][js][g] = __builtin_amdgcn_mfma_f32_16x16x32_bf16(ah[mt], bh, acc[mt][js][g], 0, 0, 0);
                    acc[mt][js][g] = __builtin_amdgcn_mfma_f32_16x16x32_bf16(al[mt], bh, acc[mt][js][g], 0, 0, 0);
                    acc[mt][js][g] = __builtin_amdgcn_mfma_f32_16x16x32_bf16(ah[mt], bl, acc[mt][js][g], 0, 0, 0);
                }
            }
        }
    };

    // ---------------- pipelined K loop (2x unrolled, named reg slots) -------
    if constexpr (LVL0) {
        float4 eA[MT][2], eB[MT][2];
        loadA0(eA, 0);
        stageB(sB0, 0);
        __syncthreads();                       // vmcnt(0): eA + sB0 ready
        for (int kt = 0; kt < KT; kt += 2) {
            loadA0(eB, kt + 1);
            stageB(sB1, kt + 1);
            {
                bf16x8 ah[MT], al[MT];
                cvtA0(eA, ah, al);
                mfma_all(ah, al, sB0);
            }
            __syncthreads();
            if (kt + 2 < KT) { loadA0(eA, kt + 2); stageB(sB0, kt + 2); }
            {
                bf16x8 ah[MT], al[MT];
                cvtA0(eB, ah, al);
                mfma_all(ah, al, sB1);
            }
            __syncthreads();
        }
    } else {
        bf16x8 hA[MT], lA[MT], hB[MT], lB[MT];
        loadAn(hA, lA, 0);
        stageB(sB0, 0);
        __syncthreads();
        for (int kt = 0; kt < KT; kt += 2) {
            loadAn(hB, lB, kt + 1);
            stageB(sB1, kt + 1);
            mfma_all(hA, lA, sB0);
            __syncthreads();
            if (kt + 2 < KT) { loadAn(hA, lA, kt + 2); stageB(sB0, kt + 2); }
            mfma_all(hB, lB, sB1);
            __syncthreads();
        }
    }

    // ---------------- fused cell epilogue ----------------
    const int d0 = (jn * JT) * 16 + l15;
    float bg[JT][NGATE];
    #pragma unroll
    for (int js = 0; js < JT; ++js)
        #pragma unroll
        for (int g = 0; g < NGATE; ++g) bg[js][g] = b[g * 256 + d0 + js * 16];

    #pragma unroll
    for (int mt = 0; mt < MT; ++mt) {
        int rb = r0 + wave * (MT * 16) + mt * 16 + quad * 4;
        #pragma unroll
        for (int v = 0; v < 4; ++v) {
            int row = rb + v;
            if (row < n) {
                #pragma unroll
                for (int js = 0; js < JT; ++js) {
                    int d = d0 + js * 16;
                    float gi = acc[mt][js][0][v] + bg[js][0];
                    float fl = acc[mt][js][1][v] + bg[js][1];
                    float fr = acc[mt][js][2][v] + bg[js][2];
                    float go = acc[mt][js][3][v] + bg[js][3];
                    float gu = acc[mt][js][4][v] + bg[js][4];
                    float cc;
                    if constexpr (LVL0) {
                        cc = sigf(gi) * tanhfast(gu);
                        (void)fl; (void)fr;
                    } else {
                        float cl = c_prev[(size_t)(2 * row) * 256 + d];
                        float cr = c_prev[(size_t)(2 * row + 1) * 256 + d];
                        cc = sigf(gi) * tanhfast(gu) + sigf(fl) * cl + sigf(fr) * cr;
                    }
                    float hh = sigf(go) * tanhfast(cc);
                    uint16_t hb = f2bf(hh);
                    h_hi_out[(size_t)row * 256 + d] = hb;
                    h_lo_out[(size_t)row * 256 + d] = f2bf(hh - bf2f(hb));
                    c_out[(size_t)row * 256 + d] = cc;
                }
            }
        }
    }
}

// ---- fused tail: levels t0..14 in one cooperative kernel -------------------
// Grid 256 blocks x 512 thr (8 waves) = 2048 waves, no LDS -> co-resident.
// Per level: wave handles (mtile, jn) tiles; A and B frags load straight
// global->VGPR (all tail data is L2-hot, ~4MB), depth-1 register dbuf over
// the 16 K-steps, 15 MFMA/step. grid.sync() between levels.
__global__ __launch_bounds__(512) void tail_kernel(
    const uint16_t* __restrict__ BuH, const uint16_t* __restrict__ BuL,
    const float* __restrict__ bias,
    uint16_t* __restrict__ h_hi, uint16_t* __restrict__ h_lo,
    float* __restrict__ cA, float* __restrict__ cB, int t0)
{
    cg::grid_group grid = cg::this_grid();
    const int lane = threadIdx.x & 63;
    const int quad = lane >> 4;
    const int l15  = lane & 15;
    const int gw   = blockIdx.x * 8 + (threadIdx.x >> 6);
    const int nw   = gridDim.x * 8;

    for (int t = t0; t <= 14; ++t) {
        const int n = 16384 >> t;
        const size_t offp = 32768 - (32768 >> (t - 1));   // off[t-1]
        const size_t offc = 32768 - (32768 >> t);         // off[t]
        const uint16_t* Ah = h_hi + offp * 256;           // row r -> h[2r],h[2r+1] contiguous (K=512)
        const uint16_t* Al = h_lo + offp * 256;
        const float* c_in  = (t & 1) ? cA : cB;
        float*       c_out = (t & 1) ? cB : cA;
        const int mtiles = (n + 15) >> 4;

        for (int tile = gw; tile < mtiles * 16; tile += nw) {
            const int mt = tile >> 4;
            const int jn = tile & 15;
            int rowa = mt * 16 + l15;
            if (rowa > n - 1) rowa = n - 1;
            const uint16_t* ap = Ah + (size_t)rowa * 512 + quad * 8;
            const uint16_t* lp = Al + (size_t)rowa * 512 + quad * 8;
            // B chunk for (g, jn, kt) at elem ((g*16+jn)*16 + kt)*512 + lane*8
            const uint16_t* bH = BuH + (size_t)jn * 8192 + lane * 8;
            const uint16_t* bL = BuL + (size_t)jn * 8192 + lane * 8;

            f32x4 acc[NGATE] = {};
            bf16x8 ah0, al0, ah1, al1;
            bf16x8 bh0[NGATE], bl0[NGATE], bh1[NGATE], bl1[NGATE];

            auto ld = [&](bf16x8& ah, bf16x8& al,
                          bf16x8 (&bh)[NGATE], bf16x8 (&bl)[NGATE], int kt) {
                ah = *(const bf16x8*)(ap + kt * 32);
                al = *(const bf16x8*)(lp + kt * 32);
                #pragma unroll
                for (int g = 0; g < NGATE; ++g) {
                    bh[g] = *(const bf16x8*)(bH + (size_t)g * 131072 + kt * 512);
                    bl[g] = *(const bf16x8*)(bL + (size_t)g * 131072 + kt * 512);
                }
            };
            auto step = [&](const bf16x8& ah, const bf16x8& al,
                            const bf16x8 (&bh)[NGATE], const bf16x8 (&bl)[NGATE]) {
                #pragma unroll
                for (int g = 0; g < NGATE; ++g) {
                    acc[g] = __builtin_amdgcn_mfma_f32_16x16x32_bf16(ah, bh[g], acc[g], 0, 0, 0);
                    acc[g] = __builtin_amdgcn_mfma_f32_16x16x32_bf16(al, bh[g], acc[g], 0, 0, 0);
                    acc[g] = __builtin_amdgcn_mfma_f32_16x16x32_bf16(ah, bl[g], acc[g], 0, 0, 0);
                }
            };

            ld(ah0, al0, bh0, bl0, 0);
            #pragma unroll
            for (int kt = 0; kt < 16; kt += 2) {
                ld(ah1, al1, bh1, bl1, kt + 1);
                step(ah0, al0, bh0, bl0);
                if (kt + 2 < 16) ld(ah0, al0, bh0, bl0, kt + 2);
                step(ah1, al1, bh1, bl1);
            }

            // fused cell epilogue
            const int d = jn * 16 + l15;
            #pragma unroll
            for (int v = 0; v < 4; ++v) {
                int row = mt * 16 + quad * 4 + v;
                if (row < n) {
                    float gi = acc[0][v] + bias[0 * 256 + d];
                    float fl = acc[1][v] + bias[1 * 256 + d];
                    float fr = acc[2][v] + bias[2 * 256 + d];
                    float go = acc[3][v] + bias[3 * 256 + d];
                    float gu = acc[4][v] + bias[4 * 256 + d];
                    float cl = c_in[(size_t)(2 * row) * 256 + d];
                    float cr = c_in[(size_t)(2 * row + 1) * 256 + d];
                    float cc = sigf(gi) * tanhfast(gu) + sigf(fl) * cl + sigf(fr) * cr;
                    float hh = sigf(go) * tanhfast(cc);
                    uint16_t hb = f2bf(hh);
                    h_hi[(offc + row) * 256 + d] = hb;
                    h_lo[(offc + row) * 256 + d] = f2bf(hh - bf2f(hb));
                    c_out[(size_t)row * 256 + d] = cc;
                }
            }
        }
        __threadfence();
        if (t < 14) grid.sync();
    }
}

// ---- projection: out = hidden @ Wp + bp, hidden reconstructed hi+lo --------
__global__ __launch_bounds__(256) void proj_kernel(
    const uint16_t* __restrict__ h_hi, const uint16_t* __restrict__ h_lo,
    const float* __restrict__ Wp, const float* __restrict__ bp,
    float* __restrict__ out, int n)
{
    const int wave = blockIdx.x * 4 + (threadIdx.x >> 6);
    const int lane = threadIdx.x & 63;
    if (wave >= n) return;

    const uint16_t* hh = h_hi + (size_t)wave * 256;
    const uint16_t* hl = h_lo + (size_t)wave * 256;
    float s[5] = {0.f, 0.f, 0.f, 0.f, 0.f};
    #pragma unroll
    for (int q = 0; q < 4; ++q) {
        int dd = lane + 64 * q;
        float hv = bf2f(hh[dd]) + bf2f(hl[dd]);
        #pragma unroll
        for (int j = 0; j < 5; ++j) s[j] += hv * Wp[dd * 5 + j];
    }
    #pragma unroll
    for (int off = 32; off; off >>= 1)
        #pragma unroll
        for (int j = 0; j < 5; ++j) s[j] += __shfl_down(s[j], off);

    if (lane == 0) {
        #pragma unroll
        for (int j = 0; j < 5; ++j) out[(size_t)wave * 5 + j] = s[j] + bp[j];
    }
}

extern "C" void kernel_launch(void* const* d_in, const int* in_sizes, int n_in,
                              void* d_out, int out_size, void* d_ws, size_t ws_size,
                              hipStream_t stream)
{
    const int*   tokens = (const int*)  d_in[0];
    const float* emb    = (const float*)d_in[1];
    const float* Wx     = (const float*)d_in[2];
    const float* Ul     = (const float*)d_in[3];
    const float* Ur     = (const float*)d_in[4];
    const float* b      = (const float*)d_in[5];
    const float* Wp     = (const float*)d_in[6];
    const float* bp     = (const float*)d_in[7];
    float* out = (float*)d_out;

    // workspace carve (total ~62.6 MB)
    uint8_t* w = (uint8_t*)d_ws;
    uint16_t* h_hi = (uint16_t*)w;  w += (size_t)32767 * 256 * 2;
    uint16_t* h_lo = (uint16_t*)w;  w += (size_t)32767 * 256 * 2;
    float*    cA   = (float*)w;     w += (size_t)16384 * 256 * 4;
    float*    cB   = (float*)w;     w += (size_t)8192  * 256 * 4;
    uint16_t* BxH  = (uint16_t*)w;  w += (size_t)80 * 8  * 64 * 8 * 2;
    uint16_t* BxL  = (uint16_t*)w;  w += (size_t)80 * 8  * 64 * 8 * 2;
    uint16_t* BuH  = (uint16_t*)w;  w += (size_t)80 * 16 * 64 * 8 * 2;
    uint16_t* BuL  = (uint16_t*)w;  w += (size_t)80 * 16 * 64 * 8 * 2;

    pack_w_kernel<<<(80 * 8  * 64) / 256, 256, 0, stream>>>(Wx, Wx, 8,  BxH, BxL);
    pack_w_kernel<<<(80 * 16 * 64) / 256, 256, 0, stream>>>(Ul, Ur, 16, BuH, BuL);

    int off[16];
    off[0] = 0;
    for (int t = 0; t < 15; ++t) off[t + 1] = off[t] + (16384 >> t);

    // level 0: 128x(5x32) tile, JT=2 -> grid (128, 8)
    lvl_gemm<128, 8, 2, true><<<dim3(16384 / 128, 8), 256, 0, stream>>>(
        nullptr, nullptr, tokens, emb, BxH, BxL, b, nullptr,
        h_hi, h_lo, cA, 16384);

    // levels 1..TAIL_T0-1 (big): launch-based LDS kernels
    for (int t = 1; t < TAIL_T0; ++t) {
        int n = 16384 >> t;
        const uint16_t* Ah = h_hi + (size_t)off[t - 1] * 256;
        const uint16_t* Al = h_lo + (size_t)off[t - 1] * 256;
        float* c_in  = (t % 2 == 0) ? cB : cA;
        float* c_out = (t % 2 == 0) ? cA : cB;
        uint16_t* Hh = h_hi + (size_t)off[t] * 256;
        uint16_t* Hl = h_lo + (size_t)off[t] * 256;
        lvl_gemm<128, 16, 2, false><<<dim3(n / 128, 8), 256, 0, stream>>>(
            Ah, Al, nullptr, nullptr, BuH, BuL, b, c_in, Hh, Hl, c_out, n);
    }

    // levels TAIL_T0..14: one cooperative persistent kernel
    {
        int t0 = TAIL_T0;
        void* targs[] = { (void*)&BuH, (void*)&BuL, (void*)&b,
                          (void*)&h_hi, (void*)&h_lo,
                          (void*)&cA, (void*)&cB, (void*)&t0 };
        hipError_t e = hipLaunchCooperativeKernel(
            (const void*)tail_kernel, dim3(256), dim3(512), targs, 0, stream);
        if (e != hipSuccess) {
            // fallback: per-level launches (same math)
            (void)hipGetLastError();
            for (int t = TAIL_T0; t <= 14; ++t) {
                int n = 16384 >> t;
                const uint16_t* Ah = h_hi + (size_t)off[t - 1] * 256;
                const uint16_t* Al = h_lo + (size_t)off[t - 1] * 256;
                float* c_in  = (t % 2 == 0) ? cB : cA;
                float* c_out = (t % 2 == 0) ? cA : cB;
                uint16_t* Hh = h_hi + (size_t)off[t] * 256;
                uint16_t* Hl = h_lo + (size_t)off[t] * 256;
                if (n >= 2048) {
                    lvl_gemm<64, 16, 2, false><<<dim3(n / 64, 8), 256, 0, stream>>>(
                        Ah, Al, nullptr, nullptr, BuH, BuL, b, c_in, Hh, Hl, c_out, n);
                } else {
                    int gx = (n + 63) / 64; if (gx < 1) gx = 1;
                    lvl_gemm<64, 16, 1, false><<<dim3(gx, 16), 256, 0, stream>>>(
                        Ah, Al, nullptr, nullptr, BuH, BuL, b, c_in, Hh, Hl, c_out, n);
                }
            }
        }
    }

    int total = off[15];  // 32767
    proj_kernel<<<(total + 3) / 4, 256, 0, stream>>>(h_hi, h_lo, Wp, bp, out, total);
}

// Round 4
// 331.632 us; speedup vs baseline: 3.6583x; 3.6583x over previous
//
#include <hip/hip_runtime.h>
#include <hip/hip_bf16.h>
#include <math.h>
#include <stdint.h>

// TreeLSTM on MFMA: L=16384, D=256, 5 gates, 15 levels, proj to 5.
// Split-precision bf16 (hi+lo) GEMMs: A*B ~= Ahi*Bhi + Alo*Bhi + Ahi*Blo.
// R2: A wave-private -> global->VGPR dbuf; LDS holds only B (40KB).
// R4: tail levels (t>=3) use per-level split-K register kernel: 4 waves
//     split K=512, named-struct frags (no scratch), LDS cross-wave reduce.
//     (R3's cooperative grid.sync was 80x slower than launch boundaries.)

typedef __attribute__((ext_vector_type(8))) short     bf16x8;
typedef __attribute__((ext_vector_type(4))) float     f32x4;
typedef __attribute__((ext_vector_type(8))) unsigned short u16x8;

#define NGATE 5
#define TAIL_T0 3

__device__ __forceinline__ uint16_t f2bf(float f) {
    uint32_t u = __builtin_bit_cast(uint32_t, f);
    u = (u + 0x7fffu + ((u >> 16) & 1u)) >> 16;
    return (uint16_t)u;
}
__device__ __forceinline__ float bf2f(uint16_t h) {
    uint32_t u = ((uint32_t)h) << 16;
    return __builtin_bit_cast(float, u);
}
__device__ __forceinline__ float sigf(float x) { return 1.0f / (1.0f + __expf(-x)); }
__device__ __forceinline__ float tanhfast(float x) {
    float e = __expf(2.0f * x);          // bounded inputs (|x| < ~20) -> no inf
    return (e - 1.0f) / (e + 1.0f);
}

__device__ __forceinline__ void gld_lds16(const void* g, void* l) {
    __builtin_amdgcn_global_load_lds(
        (const __attribute__((address_space(1))) void*)g,
        (__attribute__((address_space(3))) void*)l,
        16, 0, 0);
}

// ---- pack weights into MFMA B-frag order, split hi/lo ----------------------
// dst[( nt*KT + kt )*64 + lane][j]  =  W[kt*32 + (lane>>4)*8 + j][nt*16 + (lane&15)]
// W rows: k<256 from W0, k>=256 from W1 (both row-major K x 1280).
__global__ __launch_bounds__(256) void pack_w_kernel(
    const float* __restrict__ W0, const float* __restrict__ W1, int KT,
    uint16_t* __restrict__ dhi, uint16_t* __restrict__ dlo)
{
    int gid = blockIdx.x * 256 + threadIdx.x;
    int total = 80 * KT * 64;
    if (gid >= total) return;
    int lane = gid & 63;
    int n  = ((gid >> 6) / KT) * 16 + (lane & 15);
    int kt = (gid >> 6) % KT;
    int k0 = kt * 32 + (lane >> 4) * 8;
    u16x8 vh, vl;
    #pragma unroll
    for (int j = 0; j < 8; ++j) {
        int k = k0 + j;
        const float* src = (k < 256) ? (W0 + (size_t)k * 1280)
                                     : (W1 + (size_t)(k - 256) * 1280);
        float v = src[n];
        uint16_t h = f2bf(v);
        vh[j] = h;
        vl[j] = f2bf(v - bf2f(h));
    }
    *(u16x8*)(dhi + (size_t)gid * 8) = vh;
    *(u16x8*)(dlo + (size_t)gid * 8) = vl;
}

// ---- fused level GEMM + LSTM cell (big levels: 0..TAIL_T0-1) ---------------
// Block: 256 thr = 4 waves. Tile: BM rows x (NGATE * JT * 16) cols.
// A fragments wave-private: global->VGPR double-buffered. B via LDS (dbuf).
template<int BM, int KT, int JT, bool LVL0>
__global__ __launch_bounds__(256) void lvl_gemm(
    const uint16_t* __restrict__ Ahi, const uint16_t* __restrict__ Alo, // row-major, stride K
    const int* __restrict__ tokens, const float* __restrict__ emb,      // LVL0 only
    const uint16_t* __restrict__ Bhi, const uint16_t* __restrict__ Blo, // packed frag order
    const float* __restrict__ b,
    const float* __restrict__ c_prev,                                    // null for LVL0
    uint16_t* __restrict__ h_hi_out, uint16_t* __restrict__ h_lo_out,
    float* __restrict__ c_out, int n)
{
    constexpr int K   = KT * 32;
    constexpr int MT  = BM / 64;          // m-tiles per wave
    constexpr int NC  = NGATE * JT * 2;   // B chunks per k-step (g x js x hi/lo)

    __shared__ __align__(16) uint16_t sB0[NC * 512];
    __shared__ __align__(16) uint16_t sB1[NC * 512];

    const int tid  = threadIdx.x;
    const int wave = tid >> 6;
    const int lane = tid & 63;
    const int quad = lane >> 4;
    const int l15  = lane & 15;
    const int r0   = blockIdx.x * BM;
    const int jn   = blockIdx.y;

    f32x4 acc[MT][JT][NGATE] = {};

    // per-lane A source pointers (fixed row, k advances by kt*32)
    const uint16_t* aph[MT];
    const uint16_t* apl[MT];
    const float*    ebase[MT];
    #pragma unroll
    for (int mt = 0; mt < MT; ++mt) {
        int row = r0 + (wave * MT + mt) * 16 + l15;
        row = min(row, n - 1);
        if constexpr (LVL0) {
            int tok = tokens[row];
            ebase[mt] = emb + (size_t)tok * 256 + quad * 8;
        } else {
            aph[mt] = Ahi + (size_t)row * K + quad * 8;
            apl[mt] = Alo + (size_t)row * K + quad * 8;
        }
    }

    auto stageB = [&](uint16_t* dB, int kt) {
        for (int c = wave; c < NC; c += 4) {
            int hl = c & 1, gj = c >> 1;                 // gj = g*JT + js
            const uint16_t* src = hl ? Blo : Bhi;
            int nt = (gj / JT) * 16 + jn * JT + (gj % JT);
            gld_lds16(src + ((size_t)(nt * KT + kt) * 64 + lane) * 8,
                      dB + c * 512);
        }
    };
    // level>=1: raw bf16x8 A loads
    auto loadAn = [&](bf16x8 (&ah)[MT], bf16x8 (&al)[MT], int kt) {
        #pragma unroll
        for (int mt = 0; mt < MT; ++mt) {
            ah[mt] = *(const bf16x8*)(aph[mt] + kt * 32);
            al[mt] = *(const bf16x8*)(apl[mt] + kt * 32);
        }
    };
    // level0: raw emb float loads (convert at consume time)
    auto loadA0 = [&](float4 (&e)[MT][2], int kt) {
        #pragma unroll
        for (int mt = 0; mt < MT; ++mt) {
            const float4* p = (const float4*)(ebase[mt] + kt * 32);
            e[mt][0] = p[0];
            e[mt][1] = p[1];
        }
    };
    auto cvtA0 = [&](const float4 (&e)[MT][2], bf16x8 (&ah)[MT], bf16x8 (&al)[MT]) {
        #pragma unroll
        for (int mt = 0; mt < MT; ++mt) {
            float fv[8];
            fv[0] = e[mt][0].x; fv[1] = e[mt][0].y; fv[2] = e[mt][0].z; fv[3] = e[mt][0].w;
            fv[4] = e[mt][1].x; fv[5] = e[mt][1].y; fv[6] = e[mt][1].z; fv[7] = e[mt][1].w;
            #pragma unroll
            for (int j = 0; j < 8; ++j) {
                uint16_t h = f2bf(fv[j]);
                ah[mt][j] = (short)h;
                al[mt][j] = (short)f2bf(fv[j] - bf2f(h));
            }
        }
    };
    auto mfma_all = [&](const bf16x8 (&ah)[MT], const bf16x8 (&al)[MT],
                        const uint16_t* Bx) {
        #pragma unroll
        for (int g = 0; g < NGATE; ++g) {
            #pragma unroll
            for (int js = 0; js < JT; ++js) {
                const uint16_t* bp = Bx + (g * JT + js) * 1024;
                bf16x8 bh = *(const bf16x8*)(bp + lane * 8);
                bf16x8 bl = *(const bf16x8*)(bp + 512 + lane * 8);
                #pragma unroll
                for (int mt = 0; mt < MT; ++mt) {
                    acc[mt][js][g] = __builtin_amdgcn_mfma_f32_16x16x32_bf16(ah[mt], bh, acc[mt][js][g], 0, 0, 0);
                    acc[mt][js][g] = __builtin_amdgcn_mfma_f32_16x16x32_bf16(al[mt], bh, acc[mt][js][g], 0, 0, 0);
                    acc[mt][js][g] = __builtin_amdgcn_mfma_f32_16x16x32_bf16(ah[mt], bl, acc[mt][js][g], 0, 0, 0);
                }
            }
        }
    };

    // ---------------- pipelined K loop (2x unrolled, named reg slots) -------
    if constexpr (LVL0) {
        float4 eA[MT][2], eB[MT][2];
        loadA0(eA, 0);
        stageB(sB0, 0);
        __syncthreads();                       // vmcnt(0): eA + sB0 ready
        for (int kt = 0; kt < KT; kt += 2) {
            loadA0(eB, kt + 1);
            stageB(sB1, kt + 1);
            {
                bf16x8 ah[MT], al[MT];
                cvtA0(eA, ah, al);
                mfma_all(ah, al, sB0);
            }
            __syncthreads();
            if (kt + 2 < KT) { loadA0(eA, kt + 2); stageB(sB0, kt + 2); }
            {
                bf16x8 ah[MT], al[MT];
                cvtA0(eB, ah, al);
                mfma_all(ah, al, sB1);
            }
            __syncthreads();
        }
    } else {
        bf16x8 hA[MT], lA[MT], hB[MT], lB[MT];
        loadAn(hA, lA, 0);
        stageB(sB0, 0);
        __syncthreads();
        for (int kt = 0; kt < KT; kt += 2) {
            loadAn(hB, lB, kt + 1);
            stageB(sB1, kt + 1);
            mfma_all(hA, lA, sB0);
            __syncthreads();
            if (kt + 2 < KT) { loadAn(hA, lA, kt + 2); stageB(sB0, kt + 2); }
            mfma_all(hB, lB, sB1);
            __syncthreads();
        }
    }

    // ---------------- fused cell epilogue ----------------
    const int d0 = (jn * JT) * 16 + l15;
    float bg[JT][NGATE];
    #pragma unroll
    for (int js = 0; js < JT; ++js)
        #pragma unroll
        for (int g = 0; g < NGATE; ++g) bg[js][g] = b[g * 256 + d0 + js * 16];

    #pragma unroll
    for (int mt = 0; mt < MT; ++mt) {
        int rb = r0 + wave * (MT * 16) + mt * 16 + quad * 4;
        #pragma unroll
        for (int v = 0; v < 4; ++v) {
            int row = rb + v;
            if (row < n) {
                #pragma unroll
                for (int js = 0; js < JT; ++js) {
                    int d = d0 + js * 16;
                    float gi = acc[mt][js][0][v] + bg[js][0];
                    float fl = acc[mt][js][1][v] + bg[js][1];
                    float fr = acc[mt][js][2][v] + bg[js][2];
                    float go = acc[mt][js][3][v] + bg[js][3];
                    float gu = acc[mt][js][4][v] + bg[js][4];
                    float cc;
                    if constexpr (LVL0) {
                        cc = sigf(gi) * tanhfast(gu);
                        (void)fl; (void)fr;
                    } else {
                        float cl = c_prev[(size_t)(2 * row) * 256 + d];
                        float cr = c_prev[(size_t)(2 * row + 1) * 256 + d];
                        cc = sigf(gi) * tanhfast(gu) + sigf(fl) * cl + sigf(fr) * cr;
                    }
                    float hh = sigf(go) * tanhfast(cc);
                    uint16_t hb = f2bf(hh);
                    h_hi_out[(size_t)row * 256 + d] = hb;
                    h_lo_out[(size_t)row * 256 + d] = f2bf(hh - bf2f(hb));
                    c_out[(size_t)row * 256 + d] = cc;
                }
            }
        }
    }
}

// ---- tail level kernel (t>=3): split-K across 4 waves, register frags ------
// Block: 256 thr = 4 waves; handles 2 m-tiles (32 rows) x 1 jn (16 cols).
// Wave w computes K-chunk kts [4w, 4w+4) fully in registers (named struct
// members -> no scratch), depth-2 prefetch. Cross-wave reduce via padded LDS.
struct TailFrags {
    bf16x8 a0h, a0l, a1h, a1l;
    bf16x8 b0h, b1h, b2h, b3h, b4h;
    bf16x8 b0l, b1l, b2l, b3l, b4l;
};

#define TL_LOAD(F, KTG) do {                                                  \
    F.a0h = *(const bf16x8*)(a0hp + (KTG) * 32);                              \
    F.a0l = *(const bf16x8*)(a0lp + (KTG) * 32);                              \
    F.a1h = *(const bf16x8*)(a1hp + (KTG) * 32);                              \
    F.a1l = *(const bf16x8*)(a1lp + (KTG) * 32);                              \
    F.b0h = *(const bf16x8*)(bHp + 0 * 131072 + (KTG) * 512);                 \
    F.b1h = *(const bf16x8*)(bHp + 1 * 131072 + (KTG) * 512);                 \
    F.b2h = *(const bf16x8*)(bHp + 2 * 131072 + (KTG) * 512);                 \
    F.b3h = *(const bf16x8*)(bHp + 3 * 131072 + (KTG) * 512);                 \
    F.b4h = *(const bf16x8*)(bHp + 4 * 131072 + (KTG) * 512);                 \
    F.b0l = *(const bf16x8*)(bLp + 0 * 131072 + (KTG) * 512);                 \
    F.b1l = *(const bf16x8*)(bLp + 1 * 131072 + (KTG) * 512);                 \
    F.b2l = *(const bf16x8*)(bLp + 2 * 131072 + (KTG) * 512);                 \
    F.b3l = *(const bf16x8*)(bLp + 3 * 131072 + (KTG) * 512);                 \
    F.b4l = *(const bf16x8*)(bLp + 4 * 131072 + (KTG) * 512);                 \
} while (0)

#define TL_MM3(ACC, AH, AL, BH, BL2)                                          \
    ACC = __builtin_amdgcn_mfma_f32_16x16x32_bf16(AH, BH, ACC, 0, 0, 0);      \
    ACC = __builtin_amdgcn_mfma_f32_16x16x32_bf16(AL, BH, ACC, 0, 0, 0);      \
    ACC = __builtin_amdgcn_mfma_f32_16x16x32_bf16(AH, BL2, ACC, 0, 0, 0);

#define TL_STEP(F) do {                                                       \
    TL_MM3(acc00, F.a0h, F.a0l, F.b0h, F.b0l)                                 \
    TL_MM3(acc01, F.a0h, F.a0l, F.b1h, F.b1l)                                 \
    TL_MM3(acc02, F.a0h, F.a0l, F.b2h, F.b2l)                                 \
    TL_MM3(acc03, F.a0h, F.a0l, F.b3h, F.b3l)                                 \
    TL_MM3(acc04, F.a0h, F.a0l, F.b4h, F.b4l)                                 \
    TL_MM3(acc10, F.a1h, F.a1l, F.b0h, F.b0l)                                 \
    TL_MM3(acc11, F.a1h, F.a1l, F.b1h, F.b1l)                                 \
    TL_MM3(acc12, F.a1h, F.a1l, F.b2h, F.b2l)                                 \
    TL_MM3(acc13, F.a1h, F.a1l, F.b3h, F.b3l)                                 \
    TL_MM3(acc14, F.a1h, F.a1l, F.b4h, F.b4l)                                 \
} while (0)

#define TL_RST(M, G, A) {                                                     \
    r[(M)*20 + (G)*4 + 0] = A[0]; r[(M)*20 + (G)*4 + 1] = A[1];               \
    r[(M)*20 + (G)*4 + 2] = A[2]; r[(M)*20 + (G)*4 + 3] = A[3]; }

#define TL_RADD(M, G, A) {                                                    \
    A[0] += r[(M)*20 + (G)*4 + 0]; A[1] += r[(M)*20 + (G)*4 + 1];             \
    A[2] += r[(M)*20 + (G)*4 + 2]; A[3] += r[(M)*20 + (G)*4 + 3]; }

#define TL_EPI(M, A0, A1, A2, A3, A4) do {                                    \
    int rb = (mt0 + (M)) * 16 + quad * 4;                                     \
    _Pragma("unroll")                                                         \
    for (int v = 0; v < 4; ++v) {                                             \
        int row = rb + v;                                                     \
        if (row < n) {                                                        \
            float gi = A0[v] + bias[0 * 256 + d];                             \
            float fl = A1[v] + bias[1 * 256 + d];                             \
            float fr = A2[v] + bias[2 * 256 + d];                             \
            float go = A3[v] + bias[3 * 256 + d];                             \
            float gu = A4[v] + bias[4 * 256 + d];                             \
            float cl = c_in[(size_t)(2 * row) * 256 + d];                     \
            float cr = c_in[(size_t)(2 * row + 1) * 256 + d];                 \
            float cc = sigf(gi) * tanhfast(gu) + sigf(fl) * cl + sigf(fr) * cr; \
            float hhv = sigf(go) * tanhfast(cc);                              \
            uint16_t hb = f2bf(hhv);                                          \
            hh_out[(size_t)row * 256 + d] = hb;                               \
            hl_out[(size_t)row * 256 + d] = f2bf(hhv - bf2f(hb));             \
            c_out[(size_t)row * 256 + d] = cc;                                \
        }                                                                     \
    }                                                                         \
} while (0)

__global__ __launch_bounds__(256) void tail_lvl(
    const uint16_t* __restrict__ Ah, const uint16_t* __restrict__ Al, // stride 512
    const uint16_t* __restrict__ BuH, const uint16_t* __restrict__ BuL,
    const float* __restrict__ bias, const float* __restrict__ c_in,
    uint16_t* __restrict__ hh_out, uint16_t* __restrict__ hl_out,
    float* __restrict__ c_out, int n)
{
    __shared__ float red[3][64][41];   // stride 41 floats: conflict-free

    const int tid  = threadIdx.x;
    const int wave = tid >> 6;
    const int lane = tid & 63;
    const int quad = lane >> 4;
    const int l15  = lane & 15;
    const int mt0  = blockIdx.x * 2;
    const int jn   = blockIdx.y;

    int row0 = mt0 * 16 + l15;        if (row0 > n - 1) row0 = n - 1;
    int row1 = (mt0 + 1) * 16 + l15;  if (row1 > n - 1) row1 = n - 1;
    const uint16_t* a0hp = Ah + (size_t)row0 * 512 + quad * 8;
    const uint16_t* a0lp = Al + (size_t)row0 * 512 + quad * 8;
    const uint16_t* a1hp = Ah + (size_t)row1 * 512 + quad * 8;
    const uint16_t* a1lp = Al + (size_t)row1 * 512 + quad * 8;
    const uint16_t* bHp  = BuH + (size_t)jn * 8192 + lane * 8;
    const uint16_t* bLp  = BuL + (size_t)jn * 8192 + lane * 8;
    const int kb = wave * 4;                       // this wave's K-chunk

    f32x4 acc00 = {}, acc01 = {}, acc02 = {}, acc03 = {}, acc04 = {};
    f32x4 acc10 = {}, acc11 = {}, acc12 = {}, acc13 = {}, acc14 = {};

    TailFrags f0, f1;
    TL_LOAD(f0, kb + 0);
    TL_LOAD(f1, kb + 1);
    TL_STEP(f0);
    TL_LOAD(f0, kb + 2);
    TL_STEP(f1);
    TL_LOAD(f1, kb + 3);
    TL_STEP(f0);
    TL_STEP(f1);

    if (wave != 0) {
        float* r = &red[wave - 1][lane][0];
        TL_RST(0, 0, acc00) TL_RST(0, 1, acc01) TL_RST(0, 2, acc02)
        TL_RST(0, 3, acc03) TL_RST(0, 4, acc04)
        TL_RST(1, 0, acc10) TL_RST(1, 1, acc11) TL_RST(1, 2, acc12)
        TL_RST(1, 3, acc13) TL_RST(1, 4, acc14)
    }
    __syncthreads();
    if (wave == 0) {
        #pragma unroll
        for (int k = 0; k < 3; ++k) {
            const float* r = &red[k][lane][0];
            TL_RADD(0, 0, acc00) TL_RADD(0, 1, acc01) TL_RADD(0, 2, acc02)
            TL_RADD(0, 3, acc03) TL_RADD(0, 4, acc04)
            TL_RADD(1, 0, acc10) TL_RADD(1, 1, acc11) TL_RADD(1, 2, acc12)
            TL_RADD(1, 3, acc13) TL_RADD(1, 4, acc14)
        }
        const int d = jn * 16 + l15;
        TL_EPI(0, acc00, acc01, acc02, acc03, acc04);
        TL_EPI(1, acc10, acc11, acc12, acc13, acc14);
    }
}

// ---- projection: out = hidden @ Wp + bp, hidden reconstructed hi+lo --------
__global__ __launch_bounds__(256) void proj_kernel(
    const uint16_t* __restrict__ h_hi, const uint16_t* __restrict__ h_lo,
    const float* __restrict__ Wp, const float* __restrict__ bp,
    float* __restrict__ out, int n)
{
    const int wave = blockIdx.x * 4 + (threadIdx.x >> 6);
    const int lane = threadIdx.x & 63;
    if (wave >= n) return;

    const uint16_t* hh = h_hi + (size_t)wave * 256;
    const uint16_t* hl = h_lo + (size_t)wave * 256;
    float s[5] = {0.f, 0.f, 0.f, 0.f, 0.f};
    #pragma unroll
    for (int q = 0; q < 4; ++q) {
        int dd = lane + 64 * q;
        float hv = bf2f(hh[dd]) + bf2f(hl[dd]);
        #pragma unroll
        for (int j = 0; j < 5; ++j) s[j] += hv * Wp[dd * 5 + j];
    }
    #pragma unroll
    for (int off = 32; off; off >>= 1)
        #pragma unroll
        for (int j = 0; j < 5; ++j) s[j] += __shfl_down(s[j], off);

    if (lane == 0) {
        #pragma unroll
        for (int j = 0; j < 5; ++j) out[(size_t)wave * 5 + j] = s[j] + bp[j];
    }
}

extern "C" void kernel_launch(void* const* d_in, const int* in_sizes, int n_in,
                              void* d_out, int out_size, void* d_ws, size_t ws_size,
                              hipStream_t stream)
{
    const int*   tokens = (const int*)  d_in[0];
    const float* emb    = (const float*)d_in[1];
    const float* Wx     = (const float*)d_in[2];
    const float* Ul     = (const float*)d_in[3];
    const float* Ur     = (const float*)d_in[4];
    const float* b      = (const float*)d_in[5];
    const float* Wp     = (const float*)d_in[6];
    const float* bp     = (const float*)d_in[7];
    float* out = (float*)d_out;

    // workspace carve (total ~62.6 MB)
    uint8_t* w = (uint8_t*)d_ws;
    uint16_t* h_hi = (uint16_t*)w;  w += (size_t)32767 * 256 * 2;
    uint16_t* h_lo = (uint16_t*)w;  w += (size_t)32767 * 256 * 2;
    float*    cA   = (float*)w;     w += (size_t)16384 * 256 * 4;
    float*    cB   = (float*)w;     w += (size_t)8192  * 256 * 4;
    uint16_t* BxH  = (uint16_t*)w;  w += (size_t)80 * 8  * 64 * 8 * 2;
    uint16_t* BxL  = (uint16_t*)w;  w += (size_t)80 * 8  * 64 * 8 * 2;
    uint16_t* BuH  = (uint16_t*)w;  w += (size_t)80 * 16 * 64 * 8 * 2;
    uint16_t* BuL  = (uint16_t*)w;  w += (size_t)80 * 16 * 64 * 8 * 2;

    pack_w_kernel<<<(80 * 8  * 64) / 256, 256, 0, stream>>>(Wx, Wx, 8,  BxH, BxL);
    pack_w_kernel<<<(80 * 16 * 64) / 256, 256, 0, stream>>>(Ul, Ur, 16, BuH, BuL);

    int off[16];
    off[0] = 0;
    for (int t = 0; t < 15; ++t) off[t + 1] = off[t] + (16384 >> t);

    // level 0: 128x(5x32) tile, JT=2 -> grid (128, 8)
    lvl_gemm<128, 8, 2, true><<<dim3(16384 / 128, 8), 256, 0, stream>>>(
        nullptr, nullptr, tokens, emb, BxH, BxL, b, nullptr,
        h_hi, h_lo, cA, 16384);

    // levels 1..TAIL_T0-1 (big): LDS-staged GEMM kernels
    for (int t = 1; t < TAIL_T0; ++t) {
        int n = 16384 >> t;
        const uint16_t* Ahp = h_hi + (size_t)off[t - 1] * 256;
        const uint16_t* Alp = h_lo + (size_t)off[t - 1] * 256;
        float* c_in  = (t % 2 == 0) ? cB : cA;
        float* c_out = (t % 2 == 0) ? cA : cB;
        uint16_t* Hh = h_hi + (size_t)off[t] * 256;
        uint16_t* Hl = h_lo + (size_t)off[t] * 256;
        lvl_gemm<128, 16, 2, false><<<dim3(n / 128, 8), 256, 0, stream>>>(
            Ahp, Alp, nullptr, nullptr, BuH, BuL, b, c_in, Hh, Hl, c_out, n);
    }

    // levels TAIL_T0..14: per-level split-K register kernels
    for (int t = TAIL_T0; t <= 14; ++t) {
        int n = 16384 >> t;
        const uint16_t* Ahp = h_hi + (size_t)off[t - 1] * 256;
        const uint16_t* Alp = h_lo + (size_t)off[t - 1] * 256;
        float* c_in  = (t % 2 == 0) ? cB : cA;
        float* c_out = (t % 2 == 0) ? cA : cB;
        uint16_t* Hh = h_hi + (size_t)off[t] * 256;
        uint16_t* Hl = h_lo + (size_t)off[t] * 256;
        int mtiles = (n + 15) >> 4;
        int gx = (mtiles + 1) >> 1;
        tail_lvl<<<dim3(gx, 16), 256, 0, stream>>>(
            Ahp, Alp, BuH, BuL, b, c_in, Hh, Hl, c_out, n);
    }

    int total = off[15];  // 32767
    proj_kernel<<<(total + 3) / 4, 256, 0, stream>>>(h_hi, h_lo, Wp, bp, out, total);
}